// Round 7
// baseline (9691.942 us; speedup 1.0000x reference)
//
#include <hip/hip_runtime.h>
#include <stdint.h>

// (B,S,V,H,O) = (64,1024,32000,1024,128). f32 inputs, f32 output.
// Persistent-LSTM v4: 256 WGs x 512 thr, 1 WG/CU (LDS 145 KB).
// WG = (bh: 32 batches) x (cb: 8 channels -> 32 gate rows i/f/g/o co-owned).
// Per step:
//   issue h loads (L2-bypass, oldest in vmcnt queue), then emb(s+1) prefetch;
//   R: gates = gx(regs) + h[s].W_hh^T; epilogue -> c(regs), h packed u64, sc1;
//   arrive (relaxed RMW, 16 counters x 16 WGs);
//   X: gx(s+1) MFMA from prefetched regs (emb misses drained here, off path);
//   release: master WG per half polls counters -> writes 16 replicated flags;
//            others poll ONE flag line (~8 WGs/line, no LLC saturation).
#define BB 64
#define SS 1024
#define HH 1024
#define NWG 256
#define NTHR 512

typedef unsigned short u16;
typedef unsigned int u32;
typedef unsigned long long u64;
typedef short bf8 __attribute__((ext_vector_type(8)));
typedef float f32x4 __attribute__((ext_vector_type(4)));

#define WL_BYTES  131072                     // 2 mats x 32 rows x 2048 K bf16
#define RED_BYTES (16 * 16 * 17 * 4)         // 16 partial tiles, padded
#define LDS_TOTAL (WL_BYTES + RED_BYTES)     // 148480 < 160 KiB -> 1 WG/CU

static __device__ __forceinline__ u16 f2bf(float f) {
    union { float f; uint32_t u; } v; v.f = f;
    return (u16)((v.u + 0x7fffu + ((v.u >> 16) & 1u)) >> 16);  // RNE
}
static __device__ __forceinline__ float bf2f(u16 u) {
    union { uint32_t u; float f; } v; v.u = ((uint32_t)u) << 16; return v.f;
}
static __device__ __forceinline__ float fsig(float x) {
    return __builtin_amdgcn_rcpf(1.f + __expf(-x));
}
static __device__ __forceinline__ float ftanh(float x) {
    return 1.f - 2.f * __builtin_amdgcn_rcpf(1.f + __expf(2.f * x));
}
static __device__ __forceinline__ bf8 pack2(f32x4 a, f32x4 b) {
    bf8 r;
    #pragma unroll
    for (int e = 0; e < 4; ++e) { r[e] = (short)f2bf(a[e]); r[4 + e] = (short)f2bf(b[e]); }
    return r;
}

// h0 f32 -> hbuf parity 0 (bf16); zero counters (idx<512) and flags (512..1535).
__global__ __launch_bounds__(256) void init_misc(
    const float* __restrict__ h0, u16* __restrict__ hbuf0, u32* __restrict__ ctr)
{
    int i = blockIdx.x * 256 + threadIdx.x;
    if (i < BB * HH) hbuf0[i] = f2bf(h0[i]);
    if (i < 1536) ctr[i] = 0u;
}

__global__ __launch_bounds__(NTHR, 1) void lstm_persist(
    const int*   __restrict__ x,     // [B,S]
    const float* __restrict__ emb,   // [V,H]
    const float* __restrict__ Wih,   // [4H,H]
    const float* __restrict__ Whh,   // [4H,H]
    const float* __restrict__ bih,   // [4H]
    const float* __restrict__ bhh,   // [4H]
    const float* __restrict__ c0,    // [B,H]
    u16*         __restrict__ hbuf,  // ws: 2 x [B,H] bf16 (parity 0 = h0)
    u32*         __restrict__ ctr)   // ws: [0..511] 16 counters / [512..1535] 32 flags
{
    extern __shared__ char smem[];
    u16* WL = (u16*)smem;            // chunk ((mat*2+nh)*32+kb)*512 + lane*8
    float (*red)[16][17] = (float (*)[16][17])(smem + WL_BYTES);

    const int tid  = threadIdx.x;
    const int wv   = tid >> 6;
    const int lane = tid & 63;
    const int n16  = lane & 15;
    const int quad = lane >> 4;
    const int bh   = blockIdx.x >> 7;       // batch half
    const int cb   = blockIdx.x & 127;      // channel block (8 channels)
    const bool master = (cb == 0);          // one releaser per half

    // ---- one-time: stage W slice into LDS (f32 -> bf16, B-frag order) ----
    for (int u = tid; u < 8192; u += NTHR) {
        int ln  = u & 63;
        int kb  = (u >> 6) & 31;
        int nh  = (u >> 11) & 1;
        int mat = u >> 12;
        int rl  = nh * 16 + (ln & 15);
        int q   = rl >> 3, j = rl & 7;
        const float* src = (mat ? Whh : Wih)
                         + (size_t)(q * HH + cb * 8 + j) * HH + kb * 32 + (ln >> 4) * 8;
        u16* dst = WL + (size_t)u * 8;
        #pragma unroll
        for (int e = 0; e < 8; ++e) dst[e] = f2bf(src[e]);
    }

    // ---- epilogue-thread constants (tid<256 owns one (b,ch)) ----
    float bias[4] = {0.f, 0.f, 0.f, 0.f};
    float creg = 0.f;
    int eb = 0, ech = 0;
    if (tid < 256) {
        int mhe = tid >> 7, m = (tid >> 3) & 15, j = tid & 7;
        eb  = bh * 32 + mhe * 16 + m;
        ech = cb * 8 + j;
        #pragma unroll
        for (int q = 0; q < 4; ++q) bias[q] = bih[q * HH + ech] + bhh[q * HH + ech];
    }

    // wave role: mh (batch 16-half), kh (K quarter of 1024); both nh per wave
    const int mh = wv >> 2, kh = wv & 3;
    const int ab = bh * 32 + mh * 16 + n16;   // A batch row (m = lane&15)
    const u16* WLx0 = WL + ((size_t)(0 * 32 + kh * 8) * 512) + lane * 8;  // Wih nh=0
    const u16* WLx1 = WL + ((size_t)(1 * 32 + kh * 8) * 512) + lane * 8;  // Wih nh=1
    const u16* WLr0 = WL + ((size_t)(2 * 32 + kh * 8) * 512) + lane * 8;  // Whh nh=0
    const u16* WLr1 = WL + ((size_t)(3 * 32 + kh * 8) * 512) + lane * 8;  // Whh nh=1

    __syncthreads();  // WL ready

    u32* myctr  = ctr + (size_t)(bh * 8 + (cb & 7)) * 32;
    u32* flags  = ctr + 512;                 // 32 replicas x 32 u32 stride

    // gx partials for the CURRENT step, carried in regs across the barrier.
    f32x4 accx0, accx1;
    {   // step 0's X-phase (pre-loop; latency uncritical)
        int xr = x[(size_t)ab * SS + 0];
        const float* ep = emb + (size_t)xr * HH + kh * 256 + quad * 8;
        f32x4 a0 = {0.f, 0.f, 0.f, 0.f}, a1 = {0.f, 0.f, 0.f, 0.f};
        #pragma unroll
        for (int t = 0; t < 8; ++t) {
            bf8 av = pack2(*(const f32x4*)(ep + t * 32), *(const f32x4*)(ep + t * 32 + 4));
            bf8 b0 = *(const bf8*)(WLx0 + t * 512);
            bf8 b1 = *(const bf8*)(WLx1 + t * 512);
            a0 = __builtin_amdgcn_mfma_f32_16x16x32_bf16(av, b0, a0, 0, 0, 0);
            a1 = __builtin_amdgcn_mfma_f32_16x16x32_bf16(av, b1, a1, 0, 0, 0);
        }
        accx0 = a0; accx1 = a1;
    }

    for (int s = 0; s < SS; ++s) {
        const bool more = (s + 1 < SS);

        // ---- issue h loads FIRST (oldest in vmcnt queue -> drained first) ----
        u64 hq[16];
        {
            const u16* hp = hbuf + (size_t)(s & 1) * BB * HH
                          + (size_t)ab * HH + kh * 256 + quad * 8;
            #pragma unroll
            for (int t = 0; t < 8; ++t) {
                hq[2 * t]     = __hip_atomic_load((const u64*)(hp + t * 32),
                                    __ATOMIC_RELAXED, __HIP_MEMORY_SCOPE_AGENT);
                hq[2 * t + 1] = __hip_atomic_load((const u64*)(hp + t * 32 + 4),
                                    __ATOMIC_RELAXED, __HIP_MEMORY_SCOPE_AGENT);
            }
        }
        // ---- emb(s+1) prefetch SECOND (drains at X-phase, off critical path) ----
        f32x4 pf[16];
        if (more) {
            int xr = x[(size_t)ab * SS + (s + 1)];
            const float* ep = emb + (size_t)xr * HH + kh * 256 + quad * 8;
            #pragma unroll
            for (int t = 0; t < 8; ++t) {
                pf[2 * t]     = *(const f32x4*)(ep + t * 32);
                pf[2 * t + 1] = *(const f32x4*)(ep + t * 32 + 4);
            }
        }

        // ---- R-phase: acc = gx + h[s].W_hh^T ----
        {
            f32x4 a0 = accx0, a1 = accx1;
            #pragma unroll
            for (int t = 0; t < 8; ++t) {
                union { u64 q[2]; bf8 v; } av;
                av.q[0] = hq[2 * t]; av.q[1] = hq[2 * t + 1];
                bf8 b0 = *(const bf8*)(WLr0 + t * 512);
                bf8 b1 = *(const bf8*)(WLr1 + t * 512);
                a0 = __builtin_amdgcn_mfma_f32_16x16x32_bf16(av.v, b0, a0, 0, 0, 0);
                a1 = __builtin_amdgcn_mfma_f32_16x16x32_bf16(av.v, b1, a1, 0, 0, 0);
            }
            const int w2 = wv * 2;     // 16 partial tiles: (mh*4+kh)*2 + nh
            #pragma unroll
            for (int r = 0; r < 4; ++r) {   // C/D: col(n)=lane&15, row(m)=quad*4+r
                red[w2 + 0][quad * 4 + r][n16] = a0[r];
                red[w2 + 1][quad * 4 + r][n16] = a1[r];
            }
        }
        __syncthreads();  // sync1: red ready

        // ---- epilogue: gates -> c,h ; h packed to u64, published sc1 ----
        if (tid < 256) {
            const int mhe = tid >> 7, m = (tid >> 3) & 15, j = tid & 7;
            float g[4];
            #pragma unroll
            for (int q = 0; q < 4; ++q) {
                const int nh = q >> 1, nn = (q & 1) * 8 + j;
                float acc = bias[q];
                #pragma unroll
                for (int k = 0; k < 4; ++k)
                    acc += red[(mhe * 4 + k) * 2 + nh][m][nn];
                g[q] = acc;
            }
            float ig = fsig(g[0]);
            float fg = fsig(g[1]);
            float gv = ftanh(g[2]);
            float og = fsig(g[3]);
            float cp = (s == 0) ? c0[(size_t)eb * HH + ech] : creg;
            float cn = fg * cp + ig * gv;
            creg = cn;
            u32 hv = f2bf(og * ftanh(cn));
            u32 p1 = (u32)__shfl_xor((int)hv, 1);
            u32 w  = hv | (p1 << 16);                 // valid at even j: ch j, j+1
            u32 wp = (u32)__shfl_xor((int)w, 2);      // at j in {0,4}: ch j+2, j+3
            if ((tid & 3) == 0) {                     // j = 0 and j = 4
                u64 dv = (u64)w | ((u64)wp << 32);
                u16* hd = hbuf + (size_t)((s + 1) & 1) * BB * HH + (size_t)eb * HH + ech;
                __hip_atomic_store((u64*)hd, dv,
                                   __ATOMIC_RELAXED, __HIP_MEMORY_SCOPE_AGENT);
            }
        }
        __syncthreads();  // sync2: ALL waves' h stores drained (vmcnt(0) @ barrier)

        if (more) {
            if (tid == 0)            // arrive: relaxed RMW (no cache maintenance)
                __hip_atomic_fetch_add(myctr, 1u, __ATOMIC_RELAXED,
                                       __HIP_MEMORY_SCOPE_AGENT);
            // X-phase from prefetched regs (emb misses drain here, off path)
            {
                f32x4 a0 = {0.f, 0.f, 0.f, 0.f}, a1 = {0.f, 0.f, 0.f, 0.f};
                #pragma unroll
                for (int t = 0; t < 8; ++t) {
                    bf8 av = pack2(pf[2 * t], pf[2 * t + 1]);
                    bf8 b0 = *(const bf8*)(WLx0 + t * 512);
                    bf8 b1 = *(const bf8*)(WLx1 + t * 512);
                    a0 = __builtin_amdgcn_mfma_f32_16x16x32_bf16(av, b0, a0, 0, 0, 0);
                    a1 = __builtin_amdgcn_mfma_f32_16x16x32_bf16(av, b1, a1, 0, 0, 0);
                }
                accx0 = a0; accx1 = a1;
            }
            if (master) {
                // master: poll the 8 counters of this half, then broadcast flags
                if (tid < 8) {
                    const u32 tgt = (u32)(s + 1) * 16u;
                    u32* pc = ctr + (size_t)(bh * 8 + tid) * 32;
                    while (__hip_atomic_load(pc, __ATOMIC_RELAXED,
                                             __HIP_MEMORY_SCOPE_AGENT) < tgt)
                        __builtin_amdgcn_s_sleep(1);
                }
                __syncthreads();     // all 8 counters confirmed
                if (tid < 16)
                    __hip_atomic_store(flags + (size_t)(bh * 16 + tid) * 32,
                                       (u32)(s + 1), __ATOMIC_RELAXED,
                                       __HIP_MEMORY_SCOPE_AGENT);
            } else {
                // non-master: poll ONE replicated flag line (~8 WGs per line)
                if (tid == 0) {
                    u32* pf1 = flags + (size_t)(bh * 16 + (cb & 15)) * 32;
                    while (__hip_atomic_load(pf1, __ATOMIC_RELAXED,
                                             __HIP_MEMORY_SCOPE_AGENT) < (u32)(s + 1))
                        __builtin_amdgcn_s_sleep(2);
                }
                __syncthreads();     // sync3: WG released
            }
            // no acquire-invalidate: h reads bypass L2; emb/x/c0 are read-only
        }
    }
}

// out[b][o] = h_last[b] . fc_W[o] + fc_b[o]; f32 out. h_last = hbuf parity 0.
__global__ __launch_bounds__(128) void fc_kernel(
    const u16*   __restrict__ h,
    const float* __restrict__ fcW,
    const float* __restrict__ fcb,
    float*       __restrict__ out)
{
    int b = blockIdx.x;
    int o = threadIdx.x;
    const u16*   hp = h + (size_t)b * HH;
    const float* wp = fcW + (size_t)o * HH;
    float acc = 0.f;
    for (int k = 0; k < HH; k += 8) {
        bf8 hv = *(const bf8*)(hp + k);
        #pragma unroll
        for (int e = 0; e < 8; ++e)
            acc += bf2f((u16)hv[e]) * wp[k + e];
    }
    out[(size_t)b * 128 + o] = acc + fcb[o];
}

extern "C" void kernel_launch(void* const* d_in, const int* in_sizes, int n_in,
                              void* d_out, int out_size, void* d_ws, size_t ws_size,
                              hipStream_t stream) {
    const int*   x   = (const int*)d_in[0];
    const float* emb = (const float*)d_in[1];
    const float* Wih = (const float*)d_in[2];
    const float* Whh = (const float*)d_in[3];
    const float* bih = (const float*)d_in[4];
    const float* bhh = (const float*)d_in[5];
    const float* fcW = (const float*)d_in[6];
    const float* fcb = (const float*)d_in[7];
    const float* h0  = (const float*)d_in[8];
    const float* c0  = (const float*)d_in[9];

    // ws: hbuf 2 x [B,H] bf16 (256 KB) | ctr+flags region 6 KB
    u16* hbuf = (u16*)d_ws;
    u32* ctr  = (u32*)((char*)d_ws + 2 * (size_t)BB * HH * sizeof(u16));

    hipFuncSetAttribute((const void*)lstm_persist,
                        hipFuncAttributeMaxDynamicSharedMemorySize, LDS_TOTAL);

    init_misc<<<256, 256, 0, stream>>>(h0, hbuf, ctr);
    lstm_persist<<<NWG, NTHR, LDS_TOTAL, stream>>>(x, emb, Wih, Whh, bih, bhh,
                                                   c0, hbuf, ctr);
    fc_kernel<<<BB, 128, 0, stream>>>(hbuf, fcW, fcb, (float*)d_out);
}

// Round 8
// 6749.731 us; speedup vs baseline: 1.4359x; 1.4359x over previous
//
#include <hip/hip_runtime.h>
#include <stdint.h>

// (B,S,V,H,O) = (64,1024,32000,1024,128). f32 inputs, f32 output.
// Persistent-LSTM v5: 256 WGs x 512 thr, 1 WG/CU (LDS 145 KB).
// Key change vs v4: h(t) lives in a DISTINCT buffer per timestep (hseq[t]),
// so readers use plain CACHED loads — no address is ever re-read stale
// (first touch of hseq[t] by a reader XCD is after the step-t barrier, and
// the write-through sc1 stores are already in LLC). L2 serves the 16x
// intra-XCD broadcast; LLC h traffic drops ~16x vs the bypass path.
// Falls back to the (slow but correct) 2-buffer L2-bypass path if ws_size
// is too small for 1025 buffers.
// Barrier: per-wave arrive (s_waitcnt vmcnt(0) then relaxed RMW; 8 counters
// per half x 64 arrivals) — no sync2, no release fence, no acquire inv.
#define BB 64
#define SS 1024
#define HH 1024
#define NWG 256
#define NTHR 512
#define BBHH ((size_t)BB * HH)

typedef unsigned short u16;
typedef unsigned int u32;
typedef unsigned long long u64;
typedef short bf8 __attribute__((ext_vector_type(8)));
typedef float f32x4 __attribute__((ext_vector_type(4)));

#define WL_BYTES  131072                     // 2 mats x 32 rows x 2048 K bf16
#define RED_BYTES (16 * 16 * 17 * 4)         // 16 partial tiles, padded
#define LDS_TOTAL (WL_BYTES + RED_BYTES)     // 148480 < 160 KiB -> 1 WG/CU

static __device__ __forceinline__ u16 f2bf(float f) {
    union { float f; uint32_t u; } v; v.f = f;
    return (u16)((v.u + 0x7fffu + ((v.u >> 16) & 1u)) >> 16);  // RNE
}
static __device__ __forceinline__ float bf2f(u16 u) {
    union { uint32_t u; float f; } v; v.u = ((uint32_t)u) << 16; return v.f;
}
static __device__ __forceinline__ float fsig(float x) {
    return __builtin_amdgcn_rcpf(1.f + __expf(-x));
}
static __device__ __forceinline__ float ftanh(float x) {
    return 1.f - 2.f * __builtin_amdgcn_rcpf(1.f + __expf(2.f * x));
}
static __device__ __forceinline__ bf8 pack2(f32x4 a, f32x4 b) {
    bf8 r;
    #pragma unroll
    for (int e = 0; e < 4; ++e) { r[e] = (short)f2bf(a[e]); r[4 + e] = (short)f2bf(b[e]); }
    return r;
}

// h0 f32 -> hseq[0] (bf16); zero barrier counters.
__global__ __launch_bounds__(256) void init_misc(
    const float* __restrict__ h0, u16* __restrict__ hseq0, u32* __restrict__ ctr)
{
    int i = blockIdx.x * 256 + threadIdx.x;
    if (i < BB * HH) hseq0[i] = f2bf(h0[i]);
    if (i < 1536) ctr[i] = 0u;
}

__global__ __launch_bounds__(NTHR, 1) void lstm_persist(
    const int*   __restrict__ x,     // [B,S]
    const float* __restrict__ emb,   // [V,H]
    const float* __restrict__ Wih,   // [4H,H]
    const float* __restrict__ Whh,   // [4H,H]
    const float* __restrict__ bih,   // [4H]
    const float* __restrict__ bhh,   // [4H]
    const float* __restrict__ c0,    // [B,H]
    u16*         __restrict__ hseq,  // ws: nbuf x [B,H] bf16 (hseq[0] = h0)
    u32*         __restrict__ ctr,   // ws: 16 counters, stride 32 u32
    int cached)                      // 1: distinct buffer per step (cached reads)
{
    extern __shared__ char smem[];
    u16* WL = (u16*)smem;            // chunk ((mat*2+nh)*32+kb)*512 + lane*8
    float (*red)[16][17] = (float (*)[16][17])(smem + WL_BYTES);

    const int tid  = threadIdx.x;
    const int wv   = tid >> 6;
    const int lane = tid & 63;
    const int n16  = lane & 15;
    const int quad = lane >> 4;
    // XCD-aware swizzle (XCD = blockIdx%8 heuristic): XCDs 0-3 get bh=0,
    // 4-7 get bh=1 -> each XCD's L2 caches only ONE half's h (64 KB/step).
    const int bh   = (blockIdx.x & 7) >> 2;
    const int cb   = ((blockIdx.x >> 3) << 2) | (blockIdx.x & 3);  // 0..127

    // ---- one-time: stage W slice into LDS (f32 -> bf16, B-frag order) ----
    for (int u = tid; u < 8192; u += NTHR) {
        int ln  = u & 63;
        int kb  = (u >> 6) & 31;
        int nh  = (u >> 11) & 1;
        int mat = u >> 12;
        int rl  = nh * 16 + (ln & 15);
        int q   = rl >> 3, j = rl & 7;
        const float* src = (mat ? Whh : Wih)
                         + (size_t)(q * HH + cb * 8 + j) * HH + kb * 32 + (ln >> 4) * 8;
        u16* dst = WL + (size_t)u * 8;
        #pragma unroll
        for (int e = 0; e < 8; ++e) dst[e] = f2bf(src[e]);
    }

    // ---- epilogue-thread constants (tid<256 owns one (b,ch)) ----
    float bias[4] = {0.f, 0.f, 0.f, 0.f};
    float creg = 0.f;
    int eb = 0, ech = 0;
    if (tid < 256) {
        int mhe = tid >> 7, m = (tid >> 3) & 15, j = tid & 7;
        eb  = bh * 32 + mhe * 16 + m;
        ech = cb * 8 + j;
        #pragma unroll
        for (int q = 0; q < 4; ++q) bias[q] = bih[q * HH + ech] + bhh[q * HH + ech];
    }

    // wave role: mh (batch 16-half), kh (K quarter of 1024); both nh per wave
    const int mh = wv >> 2, kh = wv & 3;
    const int ab = bh * 32 + mh * 16 + n16;   // A batch row (m = lane&15)
    const u16* WLx0 = WL + ((size_t)(0 * 32 + kh * 8) * 512) + lane * 8;  // Wih nh=0
    const u16* WLx1 = WL + ((size_t)(1 * 32 + kh * 8) * 512) + lane * 8;  // Wih nh=1
    const u16* WLr0 = WL + ((size_t)(2 * 32 + kh * 8) * 512) + lane * 8;  // Whh nh=0
    const u16* WLr1 = WL + ((size_t)(3 * 32 + kh * 8) * 512) + lane * 8;  // Whh nh=1

    __syncthreads();  // WL ready

    u32* myctr = ctr + (size_t)(bh * 8 + (cb & 7)) * 32;   // 16 WGs x 4 waves each

    // gx partials for the CURRENT step, in regs across the barrier.
    f32x4 accx0, accx1;
    auto xphase = [&](int s1) {      // direct cached emb loads (barrier window)
        int xr = x[(size_t)ab * SS + s1];
        const float* ep = emb + (size_t)xr * HH + kh * 256 + quad * 8;
        f32x4 a0 = {0.f, 0.f, 0.f, 0.f}, a1 = {0.f, 0.f, 0.f, 0.f};
        #pragma unroll
        for (int t = 0; t < 8; ++t) {
            bf8 av = pack2(*(const f32x4*)(ep + t * 32), *(const f32x4*)(ep + t * 32 + 4));
            bf8 b0 = *(const bf8*)(WLx0 + t * 512);
            bf8 b1 = *(const bf8*)(WLx1 + t * 512);
            a0 = __builtin_amdgcn_mfma_f32_16x16x32_bf16(av, b0, a0, 0, 0, 0);
            a1 = __builtin_amdgcn_mfma_f32_16x16x32_bf16(av, b1, a1, 0, 0, 0);
        }
        accx0 = a0; accx1 = a1;
    };
    xphase(0);

    for (int s = 0; s < SS; ++s) {
        const bool more = (s + 1 < SS);
        const int  ri   = cached ? s : (s & 1);          // read buffer index
        const int  wi   = cached ? (s + 1) : ((s + 1) & 1);  // write buffer index

        // ---- R-phase: acc = gx + h[s].W_hh^T ----
        {
            const u16* hp = hseq + (size_t)ri * BBHH
                          + (size_t)ab * HH + kh * 256 + quad * 8;
            bf8 hv[8];
            if (cached) {                 // plain dwordx4, L1/L2-cacheable
                #pragma unroll
                for (int t = 0; t < 8; ++t) hv[t] = *(const bf8*)(hp + t * 32);
            } else {                      // fallback: L2-bypass atomic loads
                #pragma unroll
                for (int t = 0; t < 8; ++t) {
                    union { u64 q[2]; bf8 v; } av;
                    av.q[0] = __hip_atomic_load((const u64*)(hp + t * 32),
                                  __ATOMIC_RELAXED, __HIP_MEMORY_SCOPE_AGENT);
                    av.q[1] = __hip_atomic_load((const u64*)(hp + t * 32 + 4),
                                  __ATOMIC_RELAXED, __HIP_MEMORY_SCOPE_AGENT);
                    hv[t] = av.v;
                }
            }
            f32x4 a0 = accx0, a1 = accx1;
            #pragma unroll
            for (int t = 0; t < 8; ++t) {
                bf8 b0 = *(const bf8*)(WLr0 + t * 512);
                bf8 b1 = *(const bf8*)(WLr1 + t * 512);
                a0 = __builtin_amdgcn_mfma_f32_16x16x32_bf16(hv[t], b0, a0, 0, 0, 0);
                a1 = __builtin_amdgcn_mfma_f32_16x16x32_bf16(hv[t], b1, a1, 0, 0, 0);
            }
            const int w2 = wv * 2;     // 16 partial tiles: (mh*4+kh)*2 + nh
            #pragma unroll
            for (int r = 0; r < 4; ++r) {   // C/D: col(n)=lane&15, row(m)=quad*4+r
                red[w2 + 0][quad * 4 + r][n16] = a0[r];
                red[w2 + 1][quad * 4 + r][n16] = a1[r];
            }
        }
        __syncthreads();  // sync1: red ready

        // ---- epilogue (waves 0-3): gates -> c,h ; h packed u64, sc1 stores ----
        if (tid < 256) {
            const int mhe = tid >> 7, m = (tid >> 3) & 15, j = tid & 7;
            float g[4];
            #pragma unroll
            for (int q = 0; q < 4; ++q) {
                const int nh = q >> 1, nn = (q & 1) * 8 + j;
                float acc = bias[q];
                #pragma unroll
                for (int k = 0; k < 4; ++k)
                    acc += red[(mhe * 4 + k) * 2 + nh][m][nn];
                g[q] = acc;
            }
            float ig = fsig(g[0]);
            float fg = fsig(g[1]);
            float gv = ftanh(g[2]);
            float og = fsig(g[3]);
            float cp = (s == 0) ? c0[(size_t)eb * HH + ech] : creg;
            float cn = fg * cp + ig * gv;
            creg = cn;
            u32 hv = f2bf(og * ftanh(cn));
            u32 p1 = (u32)__shfl_xor((int)hv, 1);
            u32 w  = hv | (p1 << 16);
            u32 wp = (u32)__shfl_xor((int)w, 2);
            if ((tid & 3) == 0) {     // j in {0,4}: one u64 = 4 channels
                u64 dv = (u64)w | ((u64)wp << 32);
                u16* hd = hseq + (size_t)wi * BBHH + (size_t)eb * HH + ech;
                __hip_atomic_store((u64*)hd, dv,
                                   __ATOMIC_RELAXED, __HIP_MEMORY_SCOPE_AGENT);
            }
        }

        if (more) {
            // per-wave arrive: wait own stores' acks (vmcnt is per-wave), RMW
            if (wv < 4) {
                __builtin_amdgcn_s_waitcnt(0);
                if (lane == 0)
                    __hip_atomic_fetch_add(myctr, 1u, __ATOMIC_RELAXED,
                                           __HIP_MEMORY_SCOPE_AGENT);
            }
            // X-phase for s+1 (emb loads + MFMA hidden in the barrier window)
            xphase(s + 1);
            // wave 7: poll the 8 counters of this half directly
            if (tid >= 448 && tid < 456) {
                const u32 tgt = (u32)(s + 1) * 64u;
                u32* pc = ctr + (size_t)(bh * 8 + (tid - 448)) * 32;
                while (__hip_atomic_load(pc, __ATOMIC_RELAXED,
                                         __HIP_MEMORY_SCOPE_AGENT) < tgt)
                    __builtin_amdgcn_s_sleep(1);
            }
            __syncthreads();  // sync3: all waves released together
            // no acquire-invalidate: cached path reads never-before-touched
            // addresses; bypass path reads skip L1/L2 entirely.
        }
    }
}

// out[b][o] = h_last[b] . fc_W[o] + fc_b[o]; f32 out.
__global__ __launch_bounds__(128) void fc_kernel(
    const u16*   __restrict__ h,
    const float* __restrict__ fcW,
    const float* __restrict__ fcb,
    float*       __restrict__ out)
{
    int b = blockIdx.x;
    int o = threadIdx.x;
    const u16*   hp = h + (size_t)b * HH;
    const float* wp = fcW + (size_t)o * HH;
    float acc = 0.f;
    for (int k = 0; k < HH; k += 8) {
        bf8 hv = *(const bf8*)(hp + k);
        #pragma unroll
        for (int e = 0; e < 8; ++e)
            acc += bf2f((u16)hv[e]) * wp[k + e];
    }
    out[(size_t)b * 128 + o] = acc + fcb[o];
}

extern "C" void kernel_launch(void* const* d_in, const int* in_sizes, int n_in,
                              void* d_out, int out_size, void* d_ws, size_t ws_size,
                              hipStream_t stream) {
    const int*   x   = (const int*)d_in[0];
    const float* emb = (const float*)d_in[1];
    const float* Wih = (const float*)d_in[2];
    const float* Whh = (const float*)d_in[3];
    const float* bih = (const float*)d_in[4];
    const float* bhh = (const float*)d_in[5];
    const float* fcW = (const float*)d_in[6];
    const float* fcb = (const float*)d_in[7];
    const float* h0  = (const float*)d_in[8];
    const float* c0  = (const float*)d_in[9];

    const size_t hbytes = BBHH * sizeof(u16);                 // 128 KB per buffer
    const size_t need   = (size_t)(SS + 1) * hbytes + 8192;   // ~134.3 MB
    const int    cached = (ws_size >= need) ? 1 : 0;
    const int    nbuf   = cached ? (SS + 1) : 2;

    u16* hseq = (u16*)d_ws;
    u32* ctr  = (u32*)((char*)d_ws + (size_t)nbuf * hbytes);

    hipFuncSetAttribute((const void*)lstm_persist,
                        hipFuncAttributeMaxDynamicSharedMemorySize, LDS_TOTAL);

    init_misc<<<256, 256, 0, stream>>>(h0, hseq, ctr);
    lstm_persist<<<NWG, NTHR, LDS_TOTAL, stream>>>(x, emb, Wih, Whh, bih, bhh,
                                                   c0, hseq, ctr, cached);
    fc_kernel<<<BB, 128, 0, stream>>>(hseq + (size_t)(cached ? SS : 0) * BBHH,
                                      fcW, fcb, (float*)d_out);
}